// Round 3
// baseline (880.001 us; speedup 1.0000x reference)
//
#include <hip/hip_runtime.h>
#include <cstddef>
#include <cstdint>

#define D_DIM 2048
#define S_DIM 4096
#define B_DIM 4
#define M_DIM (B_DIM * S_DIM)   // 16384
#define N1_DIM (3 * D_DIM)      // 6144

typedef short bf16x8 __attribute__((ext_vector_type(8)));
typedef float f32x4  __attribute__((ext_vector_type(4)));

typedef const unsigned int __attribute__((address_space(1))) gu32_t;
typedef unsigned int       __attribute__((address_space(3))) lu32_t;

__device__ __forceinline__ unsigned short f2bf(float f) {
    unsigned int u = __float_as_uint(f);
    u += 0x7FFFu + ((u >> 16) & 1u);   // round-to-nearest-even (finite inputs)
    return (unsigned short)(u >> 16);
}
__device__ __forceinline__ float bf2f(unsigned short h) {
    return __uint_as_float(((unsigned int)h) << 16);
}

// ---------- fp32 -> bf16 straight convert (8 elems/thread) ----------
__global__ void k_convert(const float* __restrict__ in, unsigned short* __restrict__ out, int n8) {
    int i = blockIdx.x * blockDim.x + threadIdx.x;
    if (i >= n8) return;
    const float4* p = (const float4*)in + (size_t)i * 2;
    float4 a = p[0];
    float4 b = p[1];
    union { unsigned short s[8]; uint4 v; } r;
    r.s[0] = f2bf(a.x); r.s[1] = f2bf(a.y); r.s[2] = f2bf(a.z); r.s[3] = f2bf(a.w);
    r.s[4] = f2bf(b.x); r.s[5] = f2bf(b.y); r.s[6] = f2bf(b.z); r.s[7] = f2bf(b.w);
    ((uint4*)out)[i] = r.v;
}

// ---------- fp32 (R x C) -> bf16 transposed (C x R) ----------
__global__ void k_transpose(const float* __restrict__ in, unsigned short* __restrict__ out,
                            int R, int C) {
    __shared__ float t[32][33];
    int c0 = blockIdx.x * 32, r0 = blockIdx.y * 32;
    int x = threadIdx.x;
    for (int yy = threadIdx.y; yy < 32; yy += 8)
        t[yy][x] = in[(size_t)(r0 + yy) * C + c0 + x];
    __syncthreads();
    for (int yy = threadIdx.y; yy < 32; yy += 8)
        out[(size_t)(c0 + yy) * R + r0 + x] = f2bf(t[x][yy]);
}

// ---------- staging: one 16 KiB half-tile (128 rows x 64 k bf16) ----------
// 512 threads x 2 x global_load_lds(16B). LDS dest linear; XOR swizzle applied
// on the per-lane GLOBAL source granule, so LDS[row][g] = global[row][g^(row&7)].
__device__ __forceinline__ void stage_half2(const unsigned short* __restrict__ src,
                                            unsigned short* lds_half,
                                            int growbase, int k0, int K, int tid) {
    const int wave = tid >> 6;
    #pragma unroll
    for (int l = 0; l < 2; ++l) {
        const int gidx = l * 512 + tid;
        const int row  = gidx >> 3;               // 0..127 within half
        const int gs   = (gidx & 7) ^ (row & 7);  // swizzled source granule
        const unsigned short* g = src + (size_t)(growbase + row) * K + k0 + gs * 8;
        __builtin_amdgcn_global_load_lds((gu32_t*)g,
            (lu32_t*)(lds_half + (l * 512 + wave * 64) * 8), 16, 0, 0);
    }
}

// ---------- bf16 GEMM (256^2, 8-phase, 3-half-ahead vmcnt(6)) ----------
// 256x256 tile, BK=64, 512 threads = 8 waves (2M x 4N), per-wave 128x64 out.
// Phase (tt,q): reads A M-band [q*64,(q+1)*64) of slot tt (wave wm gets the
// 32-row half of the band), B fully read at q==0.  Read windows: A half0 ->
// phases q=0,1; A half1 -> q=2,3; B -> q=0.  This makes the stage schedule
//   ph0:As[1]h1(2i+1)  ph1:Bs[0]h0' ph2:As[0]h0' ph3:Bs[0]h1'
//   ph4:As[0]h1'       ph5:Bs[1]h0" ph6:As[1]h0" ph7:Bs[1]h1"   ('=2i+2,"=2i+3)
// legal, with vmcnt(6) (3 halves in flight) at ph3/ph7 draining exactly the
// halves the next slot window reads.  No explicit lgkmcnt: every fragment is
// consumed by an in-phase MFMA, so compiler counted waits are sufficient and
// finer (reads retire before each trailing barrier -> stage WAR safe).
template <bool OUT_BF16>
__global__ __launch_bounds__(512, 2)
void k_gemm256(const unsigned short* __restrict__ A, const unsigned short* __restrict__ Bt,
               void* __restrict__ Cp, int N, int K) {
    __shared__ unsigned short As[2][16384];  // [slot][2 halves of 128 rows x 64 k]
    __shared__ unsigned short Bs[2][16384];

    const int tid  = threadIdx.x;
    const int lane = tid & 63;
    const int wave = tid >> 6;        // 0..7
    const int wm   = wave >> 2;       // 0..1  (M split within band)
    const int wn   = wave & 3;        // 0..3  (N split)
    const int quad = lane >> 4;
    const int rsel = lane & 15;

    // bijective XCD-aware swizzle (grid counts are multiples of 8 here)
    const int nbx  = gridDim.x;
    const int nwg  = nbx * gridDim.y;
    const int cpx  = nwg >> 3;
    const int orig = blockIdx.y * nbx + blockIdx.x;
    const int swz  = (orig & 7) * cpx + (orig >> 3);
    const int m0 = (swz / nbx) * 256;
    const int n0 = (swz % nbx) * 256;

    f32x4 acc[8][4] = {};

    const int KT = K >> 6;
    const int NI = KT >> 1;  // K multiple of 128, NI >= 2

    // prologue: 7 halves; vmcnt(6) drains the first 4 (A0h0,B0h0,B0h1,A0h1)
    stage_half2(A,  &As[0][0],        m0,       0,  K, tid);
    stage_half2(Bt, &Bs[0][0],        n0,       0,  K, tid);
    stage_half2(Bt, &Bs[0][0] + 8192, n0 + 128, 0,  K, tid);
    stage_half2(A,  &As[0][0] + 8192, m0 + 128, 0,  K, tid);
    stage_half2(Bt, &Bs[1][0],        n0,       64, K, tid);
    stage_half2(A,  &As[1][0],        m0,       64, K, tid);
    stage_half2(Bt, &Bs[1][0] + 8192, n0 + 128, 64, K, tid);
    asm volatile("s_waitcnt vmcnt(6)" ::: "memory");
    __builtin_amdgcn_s_barrier();

    for (int i = 0; i < NI; ++i) {
        const int kA  = i << 7;                        // k0 of tile 2i
        const int kS0 = (i + 1 < NI) ? kA + 128 : kA;  // tile 2i+2 (tail-clamped)
        const int kS1 = (i + 1 < NI) ? kA + 192 : kA;  // tile 2i+3 (tail-clamped)
        #pragma unroll
        for (int tt = 0; tt < 2; ++tt) {
            const unsigned short* Asl = &As[tt][0];
            const unsigned short* Bsl = &Bs[tt][0];
            bf16x8 bfr[4][2];
            #pragma unroll
            for (int q = 0; q < 4; ++q) {
                // ---- ds reads: this phase's M-band A frags (+ all B at q==0)
                bf16x8 af[2][2];
                #pragma unroll
                for (int mi = 0; mi < 2; ++mi) {
                    const int ra = q * 64 + wm * 32 + mi * 16 + rsel;
                    #pragma unroll
                    for (int kb = 0; kb < 2; ++kb) {
                        const int g = (kb * 4 + quad) ^ (ra & 7);
                        af[mi][kb] = *(const bf16x8*)&Asl[ra * 64 + g * 8];
                    }
                }
                if (q == 0) {
                    #pragma unroll
                    for (int j = 0; j < 4; ++j) {
                        const int rb = wn * 64 + j * 16 + rsel;
                        #pragma unroll
                        for (int kb = 0; kb < 2; ++kb) {
                            const int g = (kb * 4 + quad) ^ (rb & 7);
                            bfr[j][kb] = *(const bf16x8*)&Bsl[rb * 64 + g * 8];
                        }
                    }
                }
                // ---- stage exactly one half-tile (see header schedule)
                const int ph = tt * 4 + q;
                switch (ph) {
                    case 0: stage_half2(A,  &As[1][0] + 8192, m0 + 128, kA + 64, K, tid); break;
                    case 1: stage_half2(Bt, &Bs[0][0],        n0,       kS0,     K, tid); break;
                    case 2: stage_half2(A,  &As[0][0],        m0,       kS0,     K, tid); break;
                    case 3: stage_half2(Bt, &Bs[0][0] + 8192, n0 + 128, kS0,     K, tid); break;
                    case 4: stage_half2(A,  &As[0][0] + 8192, m0 + 128, kS0,     K, tid); break;
                    case 5: stage_half2(Bt, &Bs[1][0],        n0,       kS1,     K, tid); break;
                    case 6: stage_half2(A,  &As[1][0],        m0,       kS1,     K, tid); break;
                    case 7: stage_half2(Bt, &Bs[1][0] + 8192, n0 + 128, kS1,     K, tid); break;
                }
                __builtin_amdgcn_s_barrier();
                __builtin_amdgcn_s_setprio(1);
                #pragma unroll
                for (int kb = 0; kb < 2; ++kb)
                    #pragma unroll
                    for (int mi = 0; mi < 2; ++mi)
                        #pragma unroll
                        for (int j = 0; j < 4; ++j)
                            acc[q * 2 + mi][j] = __builtin_amdgcn_mfma_f32_16x16x32_bf16(
                                af[mi][kb], bfr[j][kb], acc[q * 2 + mi][j], 0, 0, 0);
                __builtin_amdgcn_s_setprio(0);
                if (q == 3) asm volatile("s_waitcnt vmcnt(6)" ::: "memory");
                __builtin_amdgcn_s_barrier();
            }
        }
    }

    // Epilogue: C/D layout col=lane&15, row=quad*4+reg (m89-verified)
    // acc[fm][j]: rows m0 + (fm>>1)*64 + wm*32 + (fm&1)*16, cols n0 + wn*64 + j*16
    #pragma unroll
    for (int fm = 0; fm < 8; ++fm) {
        #pragma unroll
        for (int j = 0; j < 4; ++j) {
            const int col  = n0 + wn * 64 + j * 16 + rsel;
            const int rowb = m0 + (fm >> 1) * 64 + wm * 32 + (fm & 1) * 16 + quad * 4;
            #pragma unroll
            for (int r = 0; r < 4; ++r) {
                const size_t off = (size_t)(rowb + r) * N + col;
                if (OUT_BF16) ((unsigned short*)Cp)[off] = f2bf(acc[fm][j][r]);
                else          ((float*)Cp)[off] = acc[fm][j][r];
            }
        }
    }
}

// ---------- bf16 GEMM (proven R0 128^2 2-barrier kernel) ----------
template <bool OUT_BF16>
__global__ __launch_bounds__(256, 2)
void k_gemm128(const unsigned short* __restrict__ A, const unsigned short* __restrict__ Bt,
               void* __restrict__ Cp, int N, int K) {
    __shared__ unsigned short As[128 * 64];
    __shared__ unsigned short Bs[128 * 64];

    const int tid  = threadIdx.x;
    const int wave = tid >> 6;
    const int lane = tid & 63;
    const int m0 = blockIdx.y * 128;
    const int n0 = blockIdx.x * 128;
    const int wm = (wave & 1) * 64;
    const int wn = (wave >> 1) * 64;

    f32x4 acc[4][4] = {};

    const int srow = lane >> 3;
    const int gd   = lane & 7;
    const int quad = lane >> 4;
    const int rsel = lane & 15;

    const int KT = K >> 6;
    for (int kt = 0; kt < KT; ++kt) {
        const int k0 = kt << 6;
        __syncthreads();
        #pragma unroll
        for (int i = 0; i < 4; ++i) {
            const int seg = i * 4 + wave;
            const int row = seg * 8 + srow;
            const int gs  = gd ^ (row & 7);
            const unsigned short* ga = A  + (size_t)(m0 + row) * K + k0 + gs * 8;
            const unsigned short* gb = Bt + (size_t)(n0 + row) * K + k0 + gs * 8;
            __builtin_amdgcn_global_load_lds((gu32_t*)ga, (lu32_t*)(As + seg * 512), 16, 0, 0);
            __builtin_amdgcn_global_load_lds((gu32_t*)gb, (lu32_t*)(Bs + seg * 512), 16, 0, 0);
        }
        __syncthreads();

        #pragma unroll
        for (int kb = 0; kb < 2; ++kb) {
            bf16x8 af[4], bfr[4];
            #pragma unroll
            for (int i = 0; i < 4; ++i) {
                const int ra = wm + i * 16 + rsel;
                const int ga = (kb * 4 + quad) ^ (ra & 7);
                af[i] = *(const bf16x8*)&As[ra * 64 + ga * 8];
                const int rb = wn + i * 16 + rsel;
                const int gb = (kb * 4 + quad) ^ (rb & 7);
                bfr[i] = *(const bf16x8*)&Bs[rb * 64 + gb * 8];
            }
            #pragma unroll
            for (int i = 0; i < 4; ++i)
                #pragma unroll
                for (int j = 0; j < 4; ++j)
                    acc[i][j] = __builtin_amdgcn_mfma_f32_16x16x32_bf16(af[i], bfr[j], acc[i][j], 0, 0, 0);
        }
    }

    #pragma unroll
    for (int i = 0; i < 4; ++i) {
        #pragma unroll
        for (int j = 0; j < 4; ++j) {
            const int col  = n0 + wn + j * 16 + rsel;
            const int rowb = m0 + wm + i * 16 + quad * 4;
            #pragma unroll
            for (int r = 0; r < 4; ++r) {
                const size_t off = (size_t)(rowb + r) * N + col;
                if (OUT_BF16) ((unsigned short*)Cp)[off] = f2bf(acc[i][j][r]);
                else          ((float*)Cp)[off] = acc[i][j][r];
            }
        }
    }
}

// ---------- gate + causal depthwise conv (L=3) ----------
__global__ void k_conv_gate(const unsigned short* __restrict__ BCx,
                            const float* __restrict__ conv_w,
                            unsigned short* __restrict__ y) {
    const int bs = blockIdx.x;
    const int s  = bs & (S_DIM - 1);
    const int d0 = threadIdx.x * 8;
    const size_t row = (size_t)bs * N1_DIM;

    union U8 { uint4 v; unsigned short s[8]; };
    float bx_m2[8], bx_m1[8], bx_0[8];
    #pragma unroll
    for (int j = 0; j < 8; ++j) { bx_m2[j] = 0.f; bx_m1[j] = 0.f; }

    U8 g, xp;
    g.v  = *(const uint4*)&BCx[row + d0];
    xp.v = *(const uint4*)&BCx[row + 2 * D_DIM + d0];
    #pragma unroll
    for (int j = 0; j < 8; ++j) bx_0[j] = bf2f(g.s[j]) * bf2f(xp.s[j]);

    if (s >= 1) {
        g.v  = *(const uint4*)&BCx[row - N1_DIM + d0];
        xp.v = *(const uint4*)&BCx[row - N1_DIM + 2 * D_DIM + d0];
        #pragma unroll
        for (int j = 0; j < 8; ++j) bx_m1[j] = bf2f(g.s[j]) * bf2f(xp.s[j]);
    }
    if (s >= 2) {
        g.v  = *(const uint4*)&BCx[row - 2 * N1_DIM + d0];
        xp.v = *(const uint4*)&BCx[row - 2 * N1_DIM + 2 * D_DIM + d0];
        #pragma unroll
        for (int j = 0; j < 8; ++j) bx_m2[j] = bf2f(g.s[j]) * bf2f(xp.s[j]);
    }

    U8 c; c.v = *(const uint4*)&BCx[row + D_DIM + d0];
    U8 r;
    #pragma unroll
    for (int j = 0; j < 8; ++j) {
        const float* w = conv_w + (size_t)(d0 + j) * 3;
        const float conv = w[0] * bx_m2[j] + w[1] * bx_m1[j] + w[2] * bx_0[j];
        r.s[j] = f2bf(bf2f(c.s[j]) * conv);
    }
    *(uint4*)&y[(size_t)bs * D_DIM + d0] = r.v;
}

extern "C" void kernel_launch(void* const* d_in, const int* in_sizes, int n_in,
                              void* d_out, int out_size, void* d_ws, size_t ws_size,
                              hipStream_t stream) {
    const float* x      = (const float*)d_in[0];   // (4,4096,2048)
    const float* W_in   = (const float*)d_in[1];   // (2048,6144)
    const float* conv_w = (const float*)d_in[2];   // (2048,3)
    const float* W_out  = (const float*)d_in[3];   // (2048,2048)
    float* out = (float*)d_out;

    // workspace layout (total ~302 MB):
    //   xb   : 16384x2048 bf16 = 64 MiB   (reused as y after GEMM1)
    //   Wt_in: 6144x2048 bf16  = 24 MiB
    //   Wt_out: 2048x2048 bf16 = 8 MiB
    //   BCx  : 16384x6144 bf16 = 192 MiB
    char* ws = (char*)d_ws;
    unsigned short* xb     = (unsigned short*)ws;
    unsigned short* Wt_in  = (unsigned short*)(ws + (size_t)67108864);
    unsigned short* Wt_out = (unsigned short*)(ws + (size_t)67108864 + 25165824);
    unsigned short* BCx    = (unsigned short*)(ws + (size_t)67108864 + 25165824 + 8388608);

    const int n8 = M_DIM * D_DIM / 8;
    k_convert<<<dim3((n8 + 255) / 256), 256, 0, stream>>>(x, xb, n8);
    k_transpose<<<dim3(N1_DIM / 32, D_DIM / 32), dim3(32, 8), 0, stream>>>(W_in, Wt_in, D_DIM, N1_DIM);
    k_transpose<<<dim3(D_DIM / 32, D_DIM / 32), dim3(32, 8), 0, stream>>>(W_out, Wt_out, D_DIM, D_DIM);

    k_gemm256<true><<<dim3(N1_DIM / 256, M_DIM / 256), 512, 0, stream>>>(xb, Wt_in, BCx, N1_DIM, D_DIM);
    k_conv_gate<<<dim3(M_DIM), 256, 0, stream>>>(BCx, conv_w, xb /* y overwrites xb */);
    k_gemm128<false><<<dim3(D_DIM / 128, M_DIM / 128), 256, 0, stream>>>(xb, Wt_out, out, D_DIM, D_DIM);
}

// Round 4
// 821.388 us; speedup vs baseline: 1.0714x; 1.0714x over previous
//
#include <hip/hip_runtime.h>
#include <cstddef>
#include <cstdint>

#define D_DIM 2048
#define S_DIM 4096
#define B_DIM 4
#define M_DIM (B_DIM * S_DIM)   // 16384
#define N1_DIM (3 * D_DIM)      // 6144
#define CHUNK 16                // s-rows per conv block

typedef short bf16x8 __attribute__((ext_vector_type(8)));
typedef float f32x4  __attribute__((ext_vector_type(4)));

typedef const unsigned int __attribute__((address_space(1))) gu32_t;
typedef unsigned int       __attribute__((address_space(3))) lu32_t;

__device__ __forceinline__ unsigned short f2bf(float f) {
    unsigned int u = __float_as_uint(f);
    u += 0x7FFFu + ((u >> 16) & 1u);   // round-to-nearest-even (finite inputs)
    return (unsigned short)(u >> 16);
}
__device__ __forceinline__ float bf2f(unsigned short h) {
    return __uint_as_float(((unsigned int)h) << 16);
}

// ---------- fp32 -> bf16 straight convert (8 elems/thread) ----------
__global__ void k_convert(const float* __restrict__ in, unsigned short* __restrict__ out, int n8) {
    int i = blockIdx.x * blockDim.x + threadIdx.x;
    if (i >= n8) return;
    const float4* p = (const float4*)in + (size_t)i * 2;
    float4 a = p[0];
    float4 b = p[1];
    union { unsigned short s[8]; uint4 v; } r;
    r.s[0] = f2bf(a.x); r.s[1] = f2bf(a.y); r.s[2] = f2bf(a.z); r.s[3] = f2bf(a.w);
    r.s[4] = f2bf(b.x); r.s[5] = f2bf(b.y); r.s[6] = f2bf(b.z); r.s[7] = f2bf(b.w);
    ((uint4*)out)[i] = r.v;
}

// ---------- fp32 (R x C) -> bf16 transposed (C x R) ----------
__global__ void k_transpose(const float* __restrict__ in, unsigned short* __restrict__ out,
                            int R, int C) {
    __shared__ float t[32][33];
    int c0 = blockIdx.x * 32, r0 = blockIdx.y * 32;
    int x = threadIdx.x;
    for (int yy = threadIdx.y; yy < 32; yy += 8)
        t[yy][x] = in[(size_t)(r0 + yy) * C + c0 + x];
    __syncthreads();
    for (int yy = threadIdx.y; yy < 32; yy += 8)
        out[(size_t)(c0 + yy) * R + r0 + x] = f2bf(t[x][yy]);
}

// ---------- bf16 GEMM: C[M,N] = A[M,K] * Bt[N,K]^T (proven 128^2 kernel) ----------
// 128x128 tile, BK=64, 4 waves (2x2), each wave 64x64 via 4x4 of 16x16x32 MFMA.
// Staging: global_load_lds width=16, XOR-swizzled source granules so the
// contiguous LDS destination still yields conflict-free ds_read_b128.
template <bool OUT_BF16>
__global__ __launch_bounds__(256, 2)
void k_gemm128(const unsigned short* __restrict__ A, const unsigned short* __restrict__ Bt,
               void* __restrict__ Cp, int N, int K) {
    __shared__ unsigned short As[128 * 64];
    __shared__ unsigned short Bs[128 * 64];

    const int tid  = threadIdx.x;
    const int wave = tid >> 6;
    const int lane = tid & 63;
    const int m0 = blockIdx.y * 128;
    const int n0 = blockIdx.x * 128;
    const int wm = (wave & 1) * 64;
    const int wn = (wave >> 1) * 64;

    f32x4 acc[4][4] = {};

    const int srow = lane >> 3;
    const int gd   = lane & 7;
    const int quad = lane >> 4;
    const int rsel = lane & 15;

    const int KT = K >> 6;
    for (int kt = 0; kt < KT; ++kt) {
        const int k0 = kt << 6;
        __syncthreads();
        #pragma unroll
        for (int i = 0; i < 4; ++i) {
            const int seg = i * 4 + wave;
            const int row = seg * 8 + srow;
            const int gs  = gd ^ (row & 7);
            const unsigned short* ga = A  + (size_t)(m0 + row) * K + k0 + gs * 8;
            const unsigned short* gb = Bt + (size_t)(n0 + row) * K + k0 + gs * 8;
            __builtin_amdgcn_global_load_lds((gu32_t*)ga, (lu32_t*)(As + seg * 512), 16, 0, 0);
            __builtin_amdgcn_global_load_lds((gu32_t*)gb, (lu32_t*)(Bs + seg * 512), 16, 0, 0);
        }
        __syncthreads();

        #pragma unroll
        for (int kb = 0; kb < 2; ++kb) {
            bf16x8 af[4], bfr[4];
            #pragma unroll
            for (int i = 0; i < 4; ++i) {
                const int ra = wm + i * 16 + rsel;
                const int ga = (kb * 4 + quad) ^ (ra & 7);
                af[i] = *(const bf16x8*)&As[ra * 64 + ga * 8];
                const int rb = wn + i * 16 + rsel;
                const int gb = (kb * 4 + quad) ^ (rb & 7);
                bfr[i] = *(const bf16x8*)&Bs[rb * 64 + gb * 8];
            }
            #pragma unroll
            for (int i = 0; i < 4; ++i)
                #pragma unroll
                for (int j = 0; j < 4; ++j)
                    acc[i][j] = __builtin_amdgcn_mfma_f32_16x16x32_bf16(af[i], bfr[j], acc[i][j], 0, 0, 0);
        }
    }

    // Epilogue: C/D layout col=lane&15, row=quad*4+reg (m89-verified)
    #pragma unroll
    for (int i = 0; i < 4; ++i) {
        #pragma unroll
        for (int j = 0; j < 4; ++j) {
            const int col  = n0 + wn + j * 16 + rsel;
            const int rowb = m0 + wm + i * 16 + quad * 4;
            #pragma unroll
            for (int r = 0; r < 4; ++r) {
                const size_t off = (size_t)(rowb + r) * N + col;
                if (OUT_BF16) ((unsigned short*)Cp)[off] = f2bf(acc[i][j][r]);
                else          ((float*)Cp)[off] = acc[i][j][r];
            }
        }
    }
}

// ---------- gate + causal depthwise conv (L=3), running-window version ----------
// Each block: one batch b, CHUNK consecutive s rows, full D via 256 threads x 8.
// bx[s-1], bx[s-2] carried in registers across the s loop, so each BCx element
// is read exactly once (plus a 2-row halo per chunk).
__global__ __launch_bounds__(256)
void k_conv_gate(const unsigned short* __restrict__ BCx,
                 const float* __restrict__ conv_w,
                 unsigned short* __restrict__ y) {
    const int blk = blockIdx.x;
    const int b   = blk / (S_DIM / CHUNK);
    const int sc  = blk % (S_DIM / CHUNK);
    const int s0  = sc * CHUNK;
    const int d0  = threadIdx.x * 8;

    union U8 { uint4 v; unsigned short s[8]; };

    // conv weights for this thread's 8 channels
    float w0[8], w1[8], w2[8];
    #pragma unroll
    for (int j = 0; j < 8; ++j) {
        const float* w = conv_w + (size_t)(d0 + j) * 3;
        w0[j] = w[0]; w1[j] = w[1]; w2[j] = w[2];
    }

    float bxm1[8], bxm2[8];
    #pragma unroll
    for (int j = 0; j < 8; ++j) { bxm1[j] = 0.f; bxm2[j] = 0.f; }

    // halo: rows s0-1, s0-2 (block-uniform branch; only first chunk skips)
    if (s0 >= 1) {  // s0 is a multiple of CHUNK>=2, so s0>=1 implies s0>=2
        U8 g, xp;
        size_t rm1 = ((size_t)b * S_DIM + s0 - 1) * N1_DIM;
        g.v  = *(const uint4*)&BCx[rm1 + d0];
        xp.v = *(const uint4*)&BCx[rm1 + 2 * D_DIM + d0];
        #pragma unroll
        for (int j = 0; j < 8; ++j) bxm1[j] = bf2f(g.s[j]) * bf2f(xp.s[j]);
        size_t rm2 = ((size_t)b * S_DIM + s0 - 2) * N1_DIM;
        g.v  = *(const uint4*)&BCx[rm2 + d0];
        xp.v = *(const uint4*)&BCx[rm2 + 2 * D_DIM + d0];
        #pragma unroll
        for (int j = 0; j < 8; ++j) bxm2[j] = bf2f(g.s[j]) * bf2f(xp.s[j]);
    }

    size_t row = ((size_t)b * S_DIM + s0) * N1_DIM;
    size_t orow = ((size_t)b * S_DIM + s0) * D_DIM;
    for (int t = 0; t < CHUNK; ++t) {
        U8 g, xp, c;
        g.v  = *(const uint4*)&BCx[row + d0];
        xp.v = *(const uint4*)&BCx[row + 2 * D_DIM + d0];
        c.v  = *(const uint4*)&BCx[row + D_DIM + d0];
        U8 r;
        #pragma unroll
        for (int j = 0; j < 8; ++j) {
            const float bx0 = bf2f(g.s[j]) * bf2f(xp.s[j]);
            const float conv = w0[j] * bxm2[j] + w1[j] * bxm1[j] + w2[j] * bx0;
            r.s[j] = f2bf(bf2f(c.s[j]) * conv);
            bxm2[j] = bxm1[j];
            bxm1[j] = bx0;
        }
        *(uint4*)&y[orow + d0] = r.v;
        row  += N1_DIM;
        orow += D_DIM;
    }
}

extern "C" void kernel_launch(void* const* d_in, const int* in_sizes, int n_in,
                              void* d_out, int out_size, void* d_ws, size_t ws_size,
                              hipStream_t stream) {
    const float* x      = (const float*)d_in[0];   // (4,4096,2048)
    const float* W_in   = (const float*)d_in[1];   // (2048,6144)
    const float* conv_w = (const float*)d_in[2];   // (2048,3)
    const float* W_out  = (const float*)d_in[3];   // (2048,2048)
    float* out = (float*)d_out;

    // workspace layout (total ~302 MB):
    //   xb   : 16384x2048 bf16 = 64 MiB   (reused as y after GEMM1)
    //   Wt_in: 6144x2048 bf16  = 24 MiB
    //   Wt_out: 2048x2048 bf16 = 8 MiB
    //   BCx  : 16384x6144 bf16 = 192 MiB
    char* ws = (char*)d_ws;
    unsigned short* xb     = (unsigned short*)ws;
    unsigned short* Wt_in  = (unsigned short*)(ws + (size_t)67108864);
    unsigned short* Wt_out = (unsigned short*)(ws + (size_t)67108864 + 25165824);
    unsigned short* BCx    = (unsigned short*)(ws + (size_t)67108864 + 25165824 + 8388608);

    const int n8 = M_DIM * D_DIM / 8;
    k_convert<<<dim3((n8 + 255) / 256), 256, 0, stream>>>(x, xb, n8);
    k_transpose<<<dim3(N1_DIM / 32, D_DIM / 32), dim3(32, 8), 0, stream>>>(W_in, Wt_in, D_DIM, N1_DIM);
    k_transpose<<<dim3(D_DIM / 32, D_DIM / 32), dim3(32, 8), 0, stream>>>(W_out, Wt_out, D_DIM, D_DIM);

    k_gemm128<true><<<dim3(N1_DIM / 128, M_DIM / 128), 256, 0, stream>>>(xb, Wt_in, BCx, N1_DIM, D_DIM);
    k_conv_gate<<<dim3(B_DIM * S_DIM / CHUNK), 256, 0, stream>>>(BCx, conv_w, xb /* y overwrites xb */);
    k_gemm128<false><<<dim3(D_DIM / 128, M_DIM / 128), 256, 0, stream>>>(xb, Wt_out, out, D_DIM, D_DIM);
}